// Round 14
// baseline (544.396 us; speedup 1.0000x reference)
//
#include <hip/hip_runtime.h>
#include <hip/hip_bf16.h>
#include <hip/hip_cooperative_groups.h>

namespace cg = cooperative_groups;

#define N_FEATS 128
#define SCAN_CHUNK 1024   // elements per scan chunk (256 thr x 4)

typedef __attribute__((ext_vector_type(8))) short bf16x8;
typedef __attribute__((ext_vector_type(4))) float f32x4;

__device__ __forceinline__ unsigned short f32_to_bf16_rne(float f) {
    unsigned u = __float_as_uint(f);
    u = u + 0x7FFFu + ((u >> 16) & 1u);   // round-to-nearest-even
    return (unsigned short)(u >> 16);
}

// fp32x8 -> bf16x8 cast helper (two float4 in, two ushort4 out)
__device__ __forceinline__ void cast8(const float4& x0, const float4& x1,
                                      ushort4& o0, ushort4& o1) {
    o0.x = f32_to_bf16_rne(x0.x); o0.y = f32_to_bf16_rne(x0.y);
    o0.z = f32_to_bf16_rne(x0.z); o0.w = f32_to_bf16_rne(x0.w);
    o1.x = f32_to_bf16_rne(x1.x); o1.y = f32_to_bf16_rne(x1.y);
    o1.z = f32_to_bf16_rne(x1.z); o1.w = f32_to_bf16_rne(x1.w);
}

#define BACC(acc, v)                                              \
    do {                                                          \
        unsigned uu;                                              \
        uu = (v).x;                                               \
        acc[0] += __uint_as_float(uu << 16);                      \
        acc[1] += __uint_as_float(uu & 0xFFFF0000u);              \
        uu = (v).y;                                               \
        acc[2] += __uint_as_float(uu << 16);                      \
        acc[3] += __uint_as_float(uu & 0xFFFF0000u);              \
        uu = (v).z;                                               \
        acc[4] += __uint_as_float(uu << 16);                      \
        acc[5] += __uint_as_float(uu & 0xFFFF0000u);              \
        uu = (v).w;                                               \
        acc[6] += __uint_as_float(uu << 16);                      \
        acc[7] += __uint_as_float(uu & 0xFFFF0000u);              \
    } while (0)

// ===========================================================================
// MEGA KERNEL (cooperative): whole GCN layer in one dispatch.
// P0: W->bf16 + zero deg | sync | P1: transform(MFMA)->Y + hist_pos | sync |
// P2: scan->row_start | sync | P3: build csr | sync | P4: gather-aggregate+bias
// Grid = 1024 blocks x 256 thr, __launch_bounds__(256,4) guarantees 4 blk/CU
// resident on 256 CUs. All phases grid-stride. No early returns (grid.sync).
// ===========================================================================
__launch_bounds__(256, 4)
__global__ void gcn_mega(const float* __restrict__ feat, const float* __restrict__ W,
                         const int* __restrict__ src, const int* __restrict__ dst,
                         const float* __restrict__ bias, float* __restrict__ out,
                         int* __restrict__ deg, int* __restrict__ row_start,
                         int* __restrict__ pos, int* __restrict__ csr_src,
                         unsigned short* __restrict__ Wb, unsigned short* __restrict__ Y,
                         int n_nodes, int n_edges, int nchunks) {
    cg::grid_group grid = cg::this_grid();
    const int t = threadIdx.x;
    const int gsize = gridDim.x * 256;
    const int gtid = blockIdx.x * 256 + t;

    // ---------------- P0: cast W -> bf16; zero deg ----------------
    for (int i = gtid; i < N_FEATS * N_FEATS / 8; i += gsize) {
        const float4* f4 = reinterpret_cast<const float4*>(W) + (size_t)i * 2;
        float4 x0 = f4[0], x1 = f4[1];
        ushort4 o0, o1;
        cast8(x0, x1, o0, o1);
        reinterpret_cast<ushort4*>(Wb)[(size_t)i * 2 + 0] = o0;
        reinterpret_cast<ushort4*>(Wb)[(size_t)i * 2 + 1] = o1;
    }
    for (int i = gtid; i < n_nodes; i += gsize) deg[i] = 0;
    grid.sync();

    // ---------------- P1: transform (MFMA) + histogram ----------------
    {   // transform: Y[m][o] = bf16(sum_k feat[m][k] * W[o][k]); wave-stride
        const int wid = gtid >> 6;
        const int nwv = gsize >> 6;
        const int lw = t & 63;
        const int lr = lw & 15;       // A row / B,D column
        const int kb = lw >> 4;       // k-block 0..3
        const int ntile = (n_nodes + 15) >> 4;
        for (int tl = wid; tl < ntile; tl += nwv) {
            const int row0 = tl << 4;
            bf16x8 afrag[4] = {};
            if (row0 + lr < n_nodes) {
                const float* aptr = feat + (size_t)(row0 + lr) * N_FEATS + kb * 8;
#pragma unroll
                for (int kk = 0; kk < 4; ++kk) {
                    float4 x0 = *reinterpret_cast<const float4*>(aptr + kk * 32);
                    float4 x1 = *reinterpret_cast<const float4*>(aptr + kk * 32 + 4);
                    ushort4 o0, o1;
                    cast8(x0, x1, o0, o1);
                    bf16x8 af;
                    af[0] = (short)o0.x; af[1] = (short)o0.y;
                    af[2] = (short)o0.z; af[3] = (short)o0.w;
                    af[4] = (short)o1.x; af[5] = (short)o1.y;
                    af[6] = (short)o1.z; af[7] = (short)o1.w;
                    afrag[kk] = af;
                }
            }
            f32x4 acc[8];
#pragma unroll
            for (int nt = 0; nt < 8; ++nt) acc[nt] = (f32x4){0.f, 0.f, 0.f, 0.f};
#pragma unroll
            for (int nt = 0; nt < 8; ++nt) {
                const unsigned short* wp = Wb + (size_t)(nt * 16 + lr) * N_FEATS + kb * 8;
#pragma unroll
                for (int kk = 0; kk < 4; ++kk) {
                    bf16x8 bfrag = *reinterpret_cast<const bf16x8*>(wp + kk * 32);
                    acc[nt] = __builtin_amdgcn_mfma_f32_16x16x32_bf16(afrag[kk], bfrag,
                                                                      acc[nt], 0, 0, 0);
                }
            }
#pragma unroll
            for (int nt = 0; nt < 8; ++nt) {
                const int col = nt * 16 + lr;
#pragma unroll
                for (int j = 0; j < 4; ++j) {
                    const int r = row0 + kb * 4 + j;
                    if (r < n_nodes)
                        Y[(size_t)r * N_FEATS + col] = f32_to_bf16_rne(acc[nt][j]);
                }
            }
        }
    }
    // histogram + per-edge slot (independent of transform)
    for (int e = gtid; e < n_edges; e += gsize) {
        int d = dst[e];
        int s = src[e];
        if ((unsigned)d < (unsigned)n_nodes && (unsigned)s < (unsigned)n_nodes)
            pos[e] = atomicAdd(&deg[d], 1);
    }
    grid.sync();

    // ---------------- P2: scan -> row_start ----------------
    if ((int)blockIdx.x < nchunks) {
        const int b = blockIdx.x;
        const int base = b * SCAN_CHUNK;
        int v = 0;
        for (int j = t; j < base; j += 256) v += deg[j];
        for (int d = 1; d < 64; d <<= 1) v += __shfl_xor(v, d, 64);
        __shared__ int owsum[4];
        __shared__ int s_off;
        if ((t & 63) == 0) owsum[t >> 6] = v;
        __syncthreads();
        if (t == 0) s_off = owsum[0] + owsum[1] + owsum[2] + owsum[3];
        __syncthreads();
        const int chunk_off = s_off;

        const int idx0 = base + t * 4;
        int x[4];
#pragma unroll
        for (int k = 0; k < 4; ++k) {
            int idx = idx0 + k;
            x[k] = (idx < n_nodes) ? deg[idx] : 0;
        }
        const int tsum = x[0] + x[1] + x[2] + x[3];
        const int lane = t & 63, w = t >> 6;
        int inc = tsum;
        for (int d = 1; d < 64; d <<= 1) {
            int sv = __shfl_up(inc, d, 64);
            if (lane >= d) inc += sv;
        }
        __shared__ int wsum[4];
        if (lane == 63) wsum[w] = inc;
        __syncthreads();
        int woff = 0;
        for (int i = 0; i < w; ++i) woff += wsum[i];

        int run = chunk_off + woff + inc - tsum;
#pragma unroll
        for (int k = 0; k < 4; ++k) {
            int idx = idx0 + k;
            if (idx < n_nodes) row_start[idx] = run;
            run += x[k];
        }
        if (t == 0 && b == nchunks - 1)
            row_start[n_nodes] = chunk_off + wsum[0] + wsum[1] + wsum[2] + wsum[3];
    }
    grid.sync();

    // ---------------- P3: build CSR (atomic-free) ----------------
    for (int e = gtid; e < n_edges; e += gsize) {
        int d = dst[e];
        int s = src[e];
        if ((unsigned)d < (unsigned)n_nodes && (unsigned)s < (unsigned)n_nodes)
            csr_src[row_start[d] + pos[e]] = s;
    }
    grid.sync();

    // ---------------- P4: gather-aggregate + bias ----------------
    {
        const int wid = gtid >> 6;
        const int nwv = gsize >> 6;
        const int lw = t & 63;
        const int qw = lw >> 4;      // quarter-wave 0..3 (edge slot)
        const int ql = lw & 15;      // 16B chunk within 256B row
        const uint4* Y4 = reinterpret_cast<const uint4*>(Y);
        for (int node = wid; node < n_nodes; node += nwv) {
            const int beg = row_start[node];
            const int end = row_start[node + 1];
            float a0[8] = {0,0,0,0,0,0,0,0};
            float a1[8] = {0,0,0,0,0,0,0,0};
            float a2[8] = {0,0,0,0,0,0,0,0};
            float a3[8] = {0,0,0,0,0,0,0,0};
            int i = beg;
            for (; i + 16 <= end; i += 16) {
                int s0 = csr_src[i + qw];
                int s1 = csr_src[i + 4 + qw];
                int s2 = csr_src[i + 8 + qw];
                int s3 = csr_src[i + 12 + qw];
                uint4 v0 = Y4[(size_t)s0 * 16 + ql];
                uint4 v1 = Y4[(size_t)s1 * 16 + ql];
                uint4 v2 = Y4[(size_t)s2 * 16 + ql];
                uint4 v3 = Y4[(size_t)s3 * 16 + ql];
                BACC(a0, v0);
                BACC(a1, v1);
                BACC(a2, v2);
                BACC(a3, v3);
            }
            for (; i + 4 <= end; i += 4) {
                int s = csr_src[i + qw];
                uint4 v = Y4[(size_t)s * 16 + ql];
                BACC(a0, v);
            }
            int rem = end - i;
            if (qw < rem) {
                int s = csr_src[i + qw];
                uint4 v = Y4[(size_t)s * 16 + ql];
                BACC(a0, v);
            }
            float r[8];
#pragma unroll
            for (int k = 0; k < 8; ++k) {
                r[k] = a0[k] + a1[k] + a2[k] + a3[k];
                r[k] += __shfl_xor(r[k], 16, 64);
                r[k] += __shfl_xor(r[k], 32, 64);
            }
            if (qw == 0) {
                const float4 b0 = *reinterpret_cast<const float4*>(bias + ql * 8);
                const float4 b1 = *reinterpret_cast<const float4*>(bias + ql * 8 + 4);
                float4* o4 = reinterpret_cast<float4*>(out + (size_t)node * N_FEATS + ql * 8);
                o4[0] = make_float4(r[0] + b0.x, r[1] + b0.y, r[2] + b0.z, r[3] + b0.w);
                o4[1] = make_float4(r[4] + b1.x, r[5] + b1.y, r[6] + b1.z, r[7] + b1.w);
            }
        }
    }
}

// ===========================================================================
// Fallback multi-kernel path (r13 pipeline) — used if coop launch fails.
// ===========================================================================
__global__ void gcn_init(const float* __restrict__ W, unsigned short* __restrict__ Wb,
                         int* __restrict__ deg, int n_nodes) {
    int t = blockIdx.x * blockDim.x + threadIdx.x;
    if (t < N_FEATS * N_FEATS / 8) {
        const float4* f4 = reinterpret_cast<const float4*>(W) + (size_t)t * 2;
        float4 x0 = f4[0], x1 = f4[1];
        ushort4 o0, o1;
        cast8(x0, x1, o0, o1);
        reinterpret_cast<ushort4*>(Wb)[(size_t)t * 2 + 0] = o0;
        reinterpret_cast<ushort4*>(Wb)[(size_t)t * 2 + 1] = o1;
    }
    int u = t - N_FEATS * N_FEATS / 8;
    if (u >= 0 && u < n_nodes) deg[u] = 0;
}

__launch_bounds__(256)
__global__ void gcn_transform_mfma(const float* __restrict__ feat,
                                   const unsigned short* __restrict__ Wb,
                                   unsigned short* __restrict__ Y,
                                   int n_nodes) {
    const long long gtid = (long long)blockIdx.x * blockDim.x + threadIdx.x;
    const int wave = (int)(gtid >> 6);
    const int row0 = wave * 16;
    if (row0 >= n_nodes) return;
    const int l = (int)(threadIdx.x & 63);
    const int lr = l & 15;
    const int kb = l >> 4;

    bf16x8 afrag[4] = {};
    if (row0 + lr < n_nodes) {
        const float* aptr = feat + (size_t)(row0 + lr) * N_FEATS + kb * 8;
#pragma unroll
        for (int kk = 0; kk < 4; ++kk) {
            float4 x0 = *reinterpret_cast<const float4*>(aptr + kk * 32);
            float4 x1 = *reinterpret_cast<const float4*>(aptr + kk * 32 + 4);
            ushort4 o0, o1;
            cast8(x0, x1, o0, o1);
            bf16x8 af;
            af[0] = (short)o0.x; af[1] = (short)o0.y;
            af[2] = (short)o0.z; af[3] = (short)o0.w;
            af[4] = (short)o1.x; af[5] = (short)o1.y;
            af[6] = (short)o1.z; af[7] = (short)o1.w;
            afrag[kk] = af;
        }
    }
    f32x4 acc[8];
#pragma unroll
    for (int nt = 0; nt < 8; ++nt) acc[nt] = (f32x4){0.f, 0.f, 0.f, 0.f};
#pragma unroll
    for (int nt = 0; nt < 8; ++nt) {
        const unsigned short* wp = Wb + (size_t)(nt * 16 + lr) * N_FEATS + kb * 8;
#pragma unroll
        for (int kk = 0; kk < 4; ++kk) {
            bf16x8 bfrag = *reinterpret_cast<const bf16x8*>(wp + kk * 32);
            acc[nt] = __builtin_amdgcn_mfma_f32_16x16x32_bf16(afrag[kk], bfrag, acc[nt], 0, 0, 0);
        }
    }
#pragma unroll
    for (int nt = 0; nt < 8; ++nt) {
        const int col = nt * 16 + lr;
#pragma unroll
        for (int j = 0; j < 4; ++j) {
            const int r = row0 + kb * 4 + j;
            if (r < n_nodes)
                Y[(size_t)r * N_FEATS + col] = f32_to_bf16_rne(acc[nt][j]);
        }
    }
}

__global__ void gcn_hist_pos(const int* __restrict__ src, const int* __restrict__ dst,
                             int* __restrict__ deg, int* __restrict__ pos,
                             int n_edges, int n_nodes) {
    int e = blockIdx.x * blockDim.x + threadIdx.x;
    if (e >= n_edges) return;
    int d = dst[e];
    int s = src[e];
    if ((unsigned)d < (unsigned)n_nodes && (unsigned)s < (unsigned)n_nodes)
        pos[e] = atomicAdd(&deg[d], 1);
}

__launch_bounds__(256)
__global__ void gcn_scan(const int* __restrict__ deg, int* __restrict__ row_start,
                         int n, int nchunks) {
    const int t = threadIdx.x;
    const int b = blockIdx.x;
    const int base = b * SCAN_CHUNK;

    int v = 0;
    for (int j = t; j < base; j += 256) v += deg[j];
    for (int d = 1; d < 64; d <<= 1) v += __shfl_xor(v, d, 64);
    __shared__ int owsum[4];
    __shared__ int s_off;
    if ((t & 63) == 0) owsum[t >> 6] = v;
    __syncthreads();
    if (t == 0) s_off = owsum[0] + owsum[1] + owsum[2] + owsum[3];
    __syncthreads();
    const int chunk_off = s_off;

    const int idx0 = base + t * 4;
    int x[4];
#pragma unroll
    for (int k = 0; k < 4; ++k) {
        int idx = idx0 + k;
        x[k] = (idx < n) ? deg[idx] : 0;
    }
    const int tsum = x[0] + x[1] + x[2] + x[3];
    const int lane = t & 63, w = t >> 6;
    int inc = tsum;
    for (int d = 1; d < 64; d <<= 1) {
        int sv = __shfl_up(inc, d, 64);
        if (lane >= d) inc += sv;
    }
    __shared__ int wsum[4];
    if (lane == 63) wsum[w] = inc;
    __syncthreads();
    int woff = 0;
    for (int i = 0; i < w; ++i) woff += wsum[i];

    int run = chunk_off + woff + inc - tsum;
#pragma unroll
    for (int k = 0; k < 4; ++k) {
        int idx = idx0 + k;
        if (idx < n) row_start[idx] = run;
        run += x[k];
    }
    if (t == 0 && b == nchunks - 1)
        row_start[n] = chunk_off + wsum[0] + wsum[1] + wsum[2] + wsum[3];
}

__global__ void gcn_build_csr_pos(const int* __restrict__ src, const int* __restrict__ dst,
                                  const int* __restrict__ row_start, const int* __restrict__ pos,
                                  int* __restrict__ csr_src, int n_edges, int n_nodes) {
    int e = blockIdx.x * blockDim.x + threadIdx.x;
    if (e >= n_edges) return;
    int d = dst[e];
    int s = src[e];
    if ((unsigned)d >= (unsigned)n_nodes || (unsigned)s >= (unsigned)n_nodes) return;
    csr_src[row_start[d] + pos[e]] = s;
}

__launch_bounds__(256)
__global__ void gcn_aggregate_bf16(const uint4* __restrict__ Y,
                                   const int* __restrict__ row_start,
                                   const int* __restrict__ csr_src,
                                   const float* __restrict__ bias,
                                   float* __restrict__ out, int n_nodes) {
    int node = blockIdx.x * 4 + (threadIdx.x >> 6);
    if (node >= n_nodes) return;
    const int l = threadIdx.x & 63;
    const int qw = l >> 4;
    const int ql = l & 15;
    int beg = row_start[node];
    int end = row_start[node + 1];

    float a0[8] = {0,0,0,0,0,0,0,0};
    float a1[8] = {0,0,0,0,0,0,0,0};
    float a2[8] = {0,0,0,0,0,0,0,0};
    float a3[8] = {0,0,0,0,0,0,0,0};

    int i = beg;
    for (; i + 16 <= end; i += 16) {
        int s0 = csr_src[i + qw];
        int s1 = csr_src[i + 4 + qw];
        int s2 = csr_src[i + 8 + qw];
        int s3 = csr_src[i + 12 + qw];
        uint4 v0 = Y[(size_t)s0 * 16 + ql];
        uint4 v1 = Y[(size_t)s1 * 16 + ql];
        uint4 v2 = Y[(size_t)s2 * 16 + ql];
        uint4 v3 = Y[(size_t)s3 * 16 + ql];
        BACC(a0, v0);
        BACC(a1, v1);
        BACC(a2, v2);
        BACC(a3, v3);
    }
    for (; i + 4 <= end; i += 4) {
        int s = csr_src[i + qw];
        uint4 v = Y[(size_t)s * 16 + ql];
        BACC(a0, v);
    }
    int rem = end - i;
    if (qw < rem) {
        int s = csr_src[i + qw];
        uint4 v = Y[(size_t)s * 16 + ql];
        BACC(a0, v);
    }

    float r[8];
#pragma unroll
    for (int k = 0; k < 8; ++k) {
        r[k] = a0[k] + a1[k] + a2[k] + a3[k];
        r[k] += __shfl_xor(r[k], 16, 64);
        r[k] += __shfl_xor(r[k], 32, 64);
    }
    if (qw == 0) {
        const float4 b0 = *reinterpret_cast<const float4*>(bias + ql * 8);
        const float4 b1 = *reinterpret_cast<const float4*>(bias + ql * 8 + 4);
        float4* o4 = reinterpret_cast<float4*>(out + (size_t)node * N_FEATS + ql * 8);
        o4[0] = make_float4(r[0] + b0.x, r[1] + b0.y, r[2] + b0.z, r[3] + b0.w);
        o4[1] = make_float4(r[4] + b1.x, r[5] + b1.y, r[6] + b1.z, r[7] + b1.w);
    }
}

// ---------------------------------------------------------------------------
// Tier C fallback: transpose-W init, atomic scatter-add, fp32 GEMM.
// ---------------------------------------------------------------------------
__global__ void gcn_init_c(const float* __restrict__ W, float* __restrict__ Wt) {
    int t = blockIdx.x * blockDim.x + threadIdx.x;
    if (t < N_FEATS * N_FEATS) {
        int o = t >> 7;
        int i = t & 127;
        Wt[i * N_FEATS + o] = W[o * N_FEATS + i];
    }
}

__global__ void gcn_scatter_add(const float* __restrict__ feat,
                                const int* __restrict__ src,
                                const int* __restrict__ dst,
                                float* __restrict__ agg,
                                int n_edges, int n_nodes) {
    long long tid = (long long)blockIdx.x * blockDim.x + threadIdx.x;
    int e = (int)(tid >> 5);
    if (e >= n_edges) return;
    int j = (int)(tid & 31);
    int s = src[e];
    int d = dst[e];
    if ((unsigned)s >= (unsigned)n_nodes || (unsigned)d >= (unsigned)n_nodes) return;
    const float4 v = *reinterpret_cast<const float4*>(feat + (size_t)s * N_FEATS + j * 4);
    float* p = agg + (size_t)d * N_FEATS + j * 4;
    atomicAdd(p + 0, v.x);
    atomicAdd(p + 1, v.y);
    atomicAdd(p + 2, v.z);
    atomicAdd(p + 3, v.w);
}

__launch_bounds__(256)
__global__ void gcn_gemm_inplace(float* __restrict__ out,
                                 const float* __restrict__ Wt,
                                 const float* __restrict__ b,
                                 int n_nodes) {
    __shared__ float a_lds[32 * N_FEATS];
    const int t = threadIdx.x;
    const int node0 = blockIdx.x * 32;
    const int rows = min(32, n_nodes - node0);

    float4* a4 = reinterpret_cast<float4*>(a_lds);
    const float4* out4 = reinterpret_cast<const float4*>(out + (size_t)node0 * N_FEATS);
    const int nflt4 = rows * (N_FEATS / 4);
    for (int idx = t; idx < nflt4; idx += 256) a4[idx] = out4[idx];
    __syncthreads();

    const int oq = t & 31;
    const int ng = t >> 5;
    const float4 bb = reinterpret_cast<const float4*>(b)[oq];
    float4 acc[4];
#pragma unroll
    for (int k = 0; k < 4; ++k) acc[k] = bb;

    const float4* Wt4 = reinterpret_cast<const float4*>(Wt);
#pragma unroll 4
    for (int i = 0; i < N_FEATS; ++i) {
        const float4 w = Wt4[i * 32 + oq];
#pragma unroll
        for (int k = 0; k < 4; ++k) {
            const float a = a_lds[(ng * 4 + k) * N_FEATS + i];
            acc[k].x += a * w.x;
            acc[k].y += a * w.y;
            acc[k].z += a * w.z;
            acc[k].w += a * w.w;
        }
    }
    __syncthreads();
#pragma unroll
    for (int k = 0; k < 4; ++k) {
        const int r = ng * 4 + k;
        if (r < rows)
            reinterpret_cast<float4*>(out + (size_t)(node0 + r) * N_FEATS)[oq] = acc[k];
    }
}

extern "C" void kernel_launch(void* const* d_in, const int* in_sizes, int n_in,
                              void* d_out, int out_size, void* d_ws, size_t ws_size,
                              hipStream_t stream) {
    const float* feature = (const float*)d_in[0];
    const int*   src     = (const int*)d_in[1];
    const int*   dst     = (const int*)d_in[2];
    const float* W       = (const float*)d_in[3];
    const float* b       = (const float*)d_in[4];
    float* out = (float*)d_out;

    int n_nodes = in_sizes[0] / N_FEATS;
    int n_edges = in_sizes[1];
    int nchunks = (n_nodes + SCAN_CHUNK - 1) / SCAN_CHUNK;

    // ---- workspace layout (256 B aligned) ----
    char* ws = (char*)d_ws;
    size_t off = 0;
    auto take = [&](size_t bytes) -> char* {
        char* p = ws + off;
        off = (off + bytes + 255) & ~(size_t)255;
        return p;
    };
    int* deg       = (int*)take((size_t)n_nodes * sizeof(int));
    int* row_start = (int*)take(((size_t)n_nodes + 1) * sizeof(int));
    int* csr_src   = (int*)take((size_t)n_edges * sizeof(int));
    unsigned short* Yb = (unsigned short*)take((size_t)n_nodes * N_FEATS * sizeof(unsigned short));
    unsigned short* Wb = (unsigned short*)take((size_t)N_FEATS * N_FEATS * sizeof(unsigned short));
    int* pos       = (int*)take((size_t)n_edges * sizeof(int));
    const bool tierA2 = (off <= ws_size);

    if (tierA2) {
        // ---- single cooperative dispatch ----
        void* args[] = {(void*)&feature, (void*)&W, (void*)&src, (void*)&dst,
                        (void*)&b, (void*)&out, (void*)&deg, (void*)&row_start,
                        (void*)&pos, (void*)&csr_src, (void*)&Wb, (void*)&Yb,
                        (void*)&n_nodes, (void*)&n_edges, (void*)&nchunks};
        hipError_t err = hipLaunchCooperativeKernel((void*)gcn_mega, dim3(1024),
                                                    dim3(256), args, 0, stream);
        if (err != hipSuccess) {
            // ---- fallback: proven 6-kernel pipeline ----
            const int init_elems = N_FEATS * N_FEATS / 8 + n_nodes;
            gcn_init<<<(init_elems + 255) / 256, 256, 0, stream>>>(W, Wb, deg, n_nodes);
            const long long nthr = (long long)((n_nodes + 15) / 16) * 64;
            gcn_transform_mfma<<<(int)((nthr + 255) / 256), 256, 0, stream>>>(
                feature, Wb, Yb, n_nodes);
            const int eblocks = (n_edges + 255) / 256;
            gcn_hist_pos<<<eblocks, 256, 0, stream>>>(src, dst, deg, pos, n_edges, n_nodes);
            gcn_scan<<<nchunks, 256, 0, stream>>>(deg, row_start, n_nodes, nchunks);
            gcn_build_csr_pos<<<eblocks, 256, 0, stream>>>(
                src, dst, row_start, pos, csr_src, n_edges, n_nodes);
            gcn_aggregate_bf16<<<(n_nodes + 3) / 4, 256, 0, stream>>>(
                reinterpret_cast<const uint4*>(Yb), row_start, csr_src, b, out, n_nodes);
        }
    } else {
        // tier C: transpose init + atomic scatter + fp32 GEMM
        float* Wt = (float*)d_ws;   // 64 KB
        gcn_init_c<<<(N_FEATS * N_FEATS + 255) / 256, 256, 0, stream>>>(W, Wt);
        hipMemsetAsync(d_out, 0, (size_t)n_nodes * N_FEATS * sizeof(float), stream);
        long long total = (long long)n_edges * 32;
        gcn_scatter_add<<<(int)((total + 255) / 256), 256, 0, stream>>>(
            feature, src, dst, out, n_edges, n_nodes);
        gcn_gemm_inplace<<<(n_nodes + 31) / 32, 256, 0, stream>>>(out, Wt, b, n_nodes);
    }
}

// Round 16
// 123.242 us; speedup vs baseline: 4.4173x; 4.4173x over previous
//
#include <hip/hip_runtime.h>
#include <hip/hip_bf16.h>

#define N_FEATS 128
#define SCAN_CHUNK 1024   // elements per scan block (256 thr x 4)

typedef __attribute__((ext_vector_type(8))) short bf16x8;
typedef __attribute__((ext_vector_type(4))) float f32x4;

__device__ __forceinline__ unsigned short f32_to_bf16_rne(float f) {
    unsigned u = __float_as_uint(f);
    u = u + 0x7FFFu + ((u >> 16) & 1u);   // round-to-nearest-even
    return (unsigned short)(u >> 16);
}

// ---------------------------------------------------------------------------
// Init: cast W->bf16 (tier A2), transpose W (fallback tiers), zero deg.
// ---------------------------------------------------------------------------
__global__ void gcn_init(const float* __restrict__ W, float* __restrict__ Wt,
                         unsigned short* __restrict__ Wb,
                         int* __restrict__ deg, int n_nodes) {
    int t = blockIdx.x * blockDim.x + threadIdx.x;
    if (t < N_FEATS * N_FEATS / 8) {             // W: 8 floats -> 8 bf16
        if (Wb) {
            const float4* f4 = reinterpret_cast<const float4*>(W) + (size_t)t * 2;
            float4 x0 = f4[0];
            float4 x1 = f4[1];
            ushort4 o0, o1;
            o0.x = f32_to_bf16_rne(x0.x); o0.y = f32_to_bf16_rne(x0.y);
            o0.z = f32_to_bf16_rne(x0.z); o0.w = f32_to_bf16_rne(x0.w);
            o1.x = f32_to_bf16_rne(x1.x); o1.y = f32_to_bf16_rne(x1.y);
            o1.z = f32_to_bf16_rne(x1.z); o1.w = f32_to_bf16_rne(x1.w);
            reinterpret_cast<ushort4*>(Wb)[(size_t)t * 2 + 0] = o0;
            reinterpret_cast<ushort4*>(Wb)[(size_t)t * 2 + 1] = o1;
        }
        return;
    }
    int t2 = t - N_FEATS * N_FEATS / 8;
    if (t2 < N_FEATS * N_FEATS) {                // transpose W (fp32 fallback GEMM)
        if (Wt) {
            int o = t2 >> 7;
            int i = t2 & 127;
            Wt[i * N_FEATS + o] = W[o * N_FEATS + i];
        }
        return;
    }
    int u = t2 - N_FEATS * N_FEATS;
    if (u < n_nodes) deg[u] = 0;                 // zero deg
}

// ---------------------------------------------------------------------------
// Transform (tier A2): Y[m][o] = bf16( sum_k feature[m][k] * W[o][k] )
// One wave per 16-row stripe; A = feature fp32 cast inline; B = Wb rows.
// mfma_f32_16x16x32_bf16: A lane row=l&15, k-chunk=l>>4; B lane col=l&15,
// k-chunk=l>>4; C/D col=l&15, row=(l>>4)*4+reg (m89-verified mapping).
// ---------------------------------------------------------------------------
__launch_bounds__(256)
__global__ void gcn_transform_mfma(const float* __restrict__ feat,
                                   const unsigned short* __restrict__ Wb,
                                   unsigned short* __restrict__ Y,
                                   int n_nodes) {
    const long long gtid = (long long)blockIdx.x * blockDim.x + threadIdx.x;
    const int wave = (int)(gtid >> 6);
    const int row0 = wave * 16;
    if (row0 >= n_nodes) return;
    const int l = (int)(threadIdx.x & 63);
    const int lr = l & 15;        // A row within stripe / B,D column
    const int kb = l >> 4;        // k-block 0..3 (8 k each)

    // ---- A frags: row row0+lr, inline fp32 -> bf16 cast ----
    bf16x8 afrag[4] = {};
    if (row0 + lr < n_nodes) {
        const float* aptr = feat + (size_t)(row0 + lr) * N_FEATS + kb * 8;
#pragma unroll
        for (int kk = 0; kk < 4; ++kk) {
            float4 x0 = *reinterpret_cast<const float4*>(aptr + kk * 32);
            float4 x1 = *reinterpret_cast<const float4*>(aptr + kk * 32 + 4);
            bf16x8 af;
            af[0] = (short)f32_to_bf16_rne(x0.x);
            af[1] = (short)f32_to_bf16_rne(x0.y);
            af[2] = (short)f32_to_bf16_rne(x0.z);
            af[3] = (short)f32_to_bf16_rne(x0.w);
            af[4] = (short)f32_to_bf16_rne(x1.x);
            af[5] = (short)f32_to_bf16_rne(x1.y);
            af[6] = (short)f32_to_bf16_rne(x1.z);
            af[7] = (short)f32_to_bf16_rne(x1.w);
            afrag[kk] = af;
        }
    }

    f32x4 acc[8];
#pragma unroll
    for (int nt = 0; nt < 8; ++nt) acc[nt] = (f32x4){0.f, 0.f, 0.f, 0.f};

#pragma unroll
    for (int nt = 0; nt < 8; ++nt) {
        const unsigned short* wp = Wb + (size_t)(nt * 16 + lr) * N_FEATS + kb * 8;
#pragma unroll
        for (int kk = 0; kk < 4; ++kk) {
            bf16x8 bfrag = *reinterpret_cast<const bf16x8*>(wp + kk * 32);
            acc[nt] = __builtin_amdgcn_mfma_f32_16x16x32_bf16(afrag[kk], bfrag, acc[nt], 0, 0, 0);
        }
    }

    // ---- epilogue: store Y bf16 ----
#pragma unroll
    for (int nt = 0; nt < 8; ++nt) {
        const int col = nt * 16 + lr;
#pragma unroll
        for (int j = 0; j < 4; ++j) {
            const int r = row0 + kb * 4 + j;
            if (r < n_nodes)
                Y[(size_t)r * N_FEATS + col] = f32_to_bf16_rne(acc[nt][j]);
        }
    }
}

// ---------------------------------------------------------------------------
// CSR pass 1: histogram AND per-edge slot position (guards both indices).
// ---------------------------------------------------------------------------
__global__ void gcn_hist_pos(const int* __restrict__ src, const int* __restrict__ dst,
                             int* __restrict__ deg, int* __restrict__ pos,
                             int n_edges, int n_nodes) {
    int e = blockIdx.x * blockDim.x + threadIdx.x;
    if (e >= n_edges) return;
    int d = dst[e];
    int s = src[e];
    if ((unsigned)d < (unsigned)n_nodes && (unsigned)s < (unsigned)n_nodes)
        pos[e] = atomicAdd(&deg[d], 1);
}

// ---------------------------------------------------------------------------
// Scan phase 1: per-chunk sums.
// ---------------------------------------------------------------------------
__launch_bounds__(256)
__global__ void gcn_scan_part(const int* __restrict__ deg, int* __restrict__ chunk_sum, int n) {
    const int t = threadIdx.x;
    const int base = blockIdx.x * SCAN_CHUNK;
    int sum = 0;
#pragma unroll
    for (int k = 0; k < 4; ++k) {
        int idx = base + k * 256 + t;
        if (idx < n) sum += deg[idx];
    }
    for (int d = 1; d < 64; d <<= 1) sum += __shfl_xor(sum, d, 64);
    __shared__ int wsum[4];
    if ((t & 63) == 0) wsum[t >> 6] = sum;
    __syncthreads();
    if (t == 0) chunk_sum[blockIdx.x] = wsum[0] + wsum[1] + wsum[2] + wsum[3];
}

// ---------------------------------------------------------------------------
// Scan phase 2: inline chunk offset + per-chunk exclusive scan.
// Last block writes row_start[n].
// ---------------------------------------------------------------------------
__launch_bounds__(256)
__global__ void gcn_scan_final(const int* __restrict__ deg, const int* __restrict__ chunk_sum,
                               int* __restrict__ row_start, int n, int nchunks) {
    const int t = threadIdx.x;
    const int b = blockIdx.x;

    int v = 0;
    for (int j = t; j < b; j += 256) v += chunk_sum[j];
    for (int d = 1; d < 64; d <<= 1) v += __shfl_xor(v, d, 64);
    __shared__ int owsum[4];
    __shared__ int s_off;
    if ((t & 63) == 0) owsum[t >> 6] = v;
    __syncthreads();
    if (t == 0) s_off = owsum[0] + owsum[1] + owsum[2] + owsum[3];
    __syncthreads();
    const int chunk_off = s_off;

    const int base = b * SCAN_CHUNK;
    const int idx0 = base + t * 4;
    int x[4];
#pragma unroll
    for (int k = 0; k < 4; ++k) {
        int idx = idx0 + k;
        x[k] = (idx < n) ? deg[idx] : 0;
    }
    const int tsum = x[0] + x[1] + x[2] + x[3];

    const int lane = t & 63, w = t >> 6;
    int inc = tsum;
    for (int d = 1; d < 64; d <<= 1) {
        int sv = __shfl_up(inc, d, 64);
        if (lane >= d) inc += sv;
    }
    __shared__ int wsum[4];
    if (lane == 63) wsum[w] = inc;
    __syncthreads();
    int woff = 0;
    for (int i = 0; i < w; ++i) woff += wsum[i];

    int run = chunk_off + woff + inc - tsum;
#pragma unroll
    for (int k = 0; k < 4; ++k) {
        int idx = idx0 + k;
        if (idx < n) row_start[idx] = run;
        run += x[k];
    }

    if (t == 0 && b == nchunks - 1)
        row_start[n] = chunk_off + wsum[0] + wsum[1] + wsum[2] + wsum[3];
}

// ---------------------------------------------------------------------------
// CSR scatter, atomic-free (uses precomputed pos).
// ---------------------------------------------------------------------------
__global__ void gcn_build_csr_pos(const int* __restrict__ src, const int* __restrict__ dst,
                                  const int* __restrict__ row_start, const int* __restrict__ pos,
                                  int* __restrict__ csr_src, int n_edges, int n_nodes) {
    int e = blockIdx.x * blockDim.x + threadIdx.x;
    if (e >= n_edges) return;
    int d = dst[e];
    int s = src[e];
    if ((unsigned)d >= (unsigned)n_nodes || (unsigned)s >= (unsigned)n_nodes) return;
    csr_src[row_start[d] + pos[e]] = s;
}

// ---------------------------------------------------------------------------
// bf16 aggregation + bias (tier A2): one wave per node, quarter-wave per
// full 256B edge-row, 4 edges/instr x 4 unrolled = 16 edges in flight.
// fp32 accumulate, shfl_xor 16/32 combine, + bias, fp32 out.
// ---------------------------------------------------------------------------
#define BACC(acc, v)                                              \
    do {                                                          \
        unsigned uu;                                              \
        uu = (v).x;                                               \
        acc[0] += __uint_as_float(uu << 16);                      \
        acc[1] += __uint_as_float(uu & 0xFFFF0000u);              \
        uu = (v).y;                                               \
        acc[2] += __uint_as_float(uu << 16);                      \
        acc[3] += __uint_as_float(uu & 0xFFFF0000u);              \
        uu = (v).z;                                               \
        acc[4] += __uint_as_float(uu << 16);                      \
        acc[5] += __uint_as_float(uu & 0xFFFF0000u);              \
        uu = (v).w;                                               \
        acc[6] += __uint_as_float(uu << 16);                      \
        acc[7] += __uint_as_float(uu & 0xFFFF0000u);              \
    } while (0)

__launch_bounds__(256)
__global__ void gcn_aggregate_bf16(const uint4* __restrict__ Y,
                                   const int* __restrict__ row_start,
                                   const int* __restrict__ csr_src,
                                   const float* __restrict__ bias,
                                   float* __restrict__ out, int n_nodes) {
    int node = blockIdx.x * 4 + (threadIdx.x >> 6);
    if (node >= n_nodes) return;
    const int l = threadIdx.x & 63;
    const int qw = l >> 4;       // quarter-wave 0..3 (edge slot)
    const int ql = l & 15;       // 16B chunk within the 256B row
    int beg = row_start[node];
    int end = row_start[node + 1];

    float a0[8] = {0,0,0,0,0,0,0,0};
    float a1[8] = {0,0,0,0,0,0,0,0};
    float a2[8] = {0,0,0,0,0,0,0,0};
    float a3[8] = {0,0,0,0,0,0,0,0};

    int i = beg;
    for (; i + 16 <= end; i += 16) {             // 16 edges per iter
        int s0 = csr_src[i + qw];
        int s1 = csr_src[i + 4 + qw];
        int s2 = csr_src[i + 8 + qw];
        int s3 = csr_src[i + 12 + qw];
        uint4 v0 = Y[(size_t)s0 * 16 + ql];
        uint4 v1 = Y[(size_t)s1 * 16 + ql];
        uint4 v2 = Y[(size_t)s2 * 16 + ql];
        uint4 v3 = Y[(size_t)s3 * 16 + ql];
        BACC(a0, v0);
        BACC(a1, v1);
        BACC(a2, v2);
        BACC(a3, v3);
    }
    for (; i + 4 <= end; i += 4) {               // groups of 4 (<=3 iters)
        int s = csr_src[i + qw];
        uint4 v = Y[(size_t)s * 16 + ql];
        BACC(a0, v);
    }
    int rem = end - i;                           // <4 leftover edges
    if (qw < rem) {
        int s = csr_src[i + qw];
        uint4 v = Y[(size_t)s * 16 + ql];
        BACC(a0, v);
    }

    float r[8];
#pragma unroll
    for (int k = 0; k < 8; ++k) {
        r[k] = a0[k] + a1[k] + a2[k] + a3[k];
        r[k] += __shfl_xor(r[k], 16, 64);
        r[k] += __shfl_xor(r[k], 32, 64);
    }

    if (qw == 0) {                               // lanes 0..15 write the row
        const float4 b0 = *reinterpret_cast<const float4*>(bias + ql * 8);
        const float4 b1 = *reinterpret_cast<const float4*>(bias + ql * 8 + 4);
        float4* o4 = reinterpret_cast<float4*>(out + (size_t)node * N_FEATS + ql * 8);
        o4[0] = make_float4(r[0] + b0.x, r[1] + b0.y, r[2] + b0.z, r[3] + b0.w);
        o4[1] = make_float4(r[4] + b1.x, r[5] + b1.y, r[6] + b1.z, r[7] + b1.w);
    }
}

// ---------------------------------------------------------------------------
// fp32 aggregation (tier A/B fallback): half-wave float4, 8 edges in flight.
// ---------------------------------------------------------------------------
__launch_bounds__(256)
__global__ void gcn_aggregate(const float* __restrict__ feat,
                              const int* __restrict__ row_start,
                              const int* __restrict__ csr_src,
                              float* __restrict__ out, int n_nodes) {
    int node = blockIdx.x * 4 + (threadIdx.x >> 6);
    if (node >= n_nodes) return;
    const int l = threadIdx.x & 63;
    const int q = l & 31;
    const int h = l >> 5;
    int beg = row_start[node];
    int end = row_start[node + 1];
    const float4* f4 = reinterpret_cast<const float4*>(feat);

    float4 a0 = make_float4(0.f, 0.f, 0.f, 0.f);
    float4 a1 = a0, a2 = a0, a3 = a0;
    int i = beg;
    for (; i + 8 <= end; i += 8) {
        int s0 = csr_src[i + h];
        int s1 = csr_src[i + 2 + h];
        int s2 = csr_src[i + 4 + h];
        int s3 = csr_src[i + 6 + h];
        float4 v0 = f4[(size_t)s0 * 32 + q];
        float4 v1 = f4[(size_t)s1 * 32 + q];
        float4 v2 = f4[(size_t)s2 * 32 + q];
        float4 v3 = f4[(size_t)s3 * 32 + q];
        a0.x += v0.x; a0.y += v0.y; a0.z += v0.z; a0.w += v0.w;
        a1.x += v1.x; a1.y += v1.y; a1.z += v1.z; a1.w += v1.w;
        a2.x += v2.x; a2.y += v2.y; a2.z += v2.z; a2.w += v2.w;
        a3.x += v3.x; a3.y += v3.y; a3.z += v3.z; a3.w += v3.w;
    }
    for (; i + 2 <= end; i += 2) {
        int s0 = csr_src[i + h];
        float4 v0 = f4[(size_t)s0 * 32 + q];
        a0.x += v0.x; a0.y += v0.y; a0.z += v0.z; a0.w += v0.w;
    }
    if (i < end && h == 0) {
        int s = csr_src[i];
        float4 v = f4[(size_t)s * 32 + q];
        a0.x += v.x; a0.y += v.y; a0.z += v.z; a0.w += v.w;
    }

    float4 acc = make_float4(a0.x + a1.x + a2.x + a3.x,
                             a0.y + a1.y + a2.y + a3.y,
                             a0.z + a1.z + a2.z + a3.z,
                             a0.w + a1.w + a2.w + a3.w);
    acc.x += __shfl_xor(acc.x, 32, 64);
    acc.y += __shfl_xor(acc.y, 32, 64);
    acc.z += __shfl_xor(acc.z, 32, 64);
    acc.w += __shfl_xor(acc.w, 32, 64);

    if (h == 0)
        reinterpret_cast<float4*>(out)[(size_t)node * 32 + q] = acc;
}

// ---------------------------------------------------------------------------
// Fallback scatter-add (tier C).
// ---------------------------------------------------------------------------
__global__ void gcn_scatter_add(const float* __restrict__ feat,
                                const int* __restrict__ src,
                                const int* __restrict__ dst,
                                float* __restrict__ agg,
                                int n_edges, int n_nodes) {
    long long tid = (long long)blockIdx.x * blockDim.x + threadIdx.x;
    int e = (int)(tid >> 5);
    if (e >= n_edges) return;
    int j = (int)(tid & 31);
    int s = src[e];
    int d = dst[e];
    if ((unsigned)s >= (unsigned)n_nodes || (unsigned)d >= (unsigned)n_nodes) return;
    const float4 v = *reinterpret_cast<const float4*>(feat + (size_t)s * N_FEATS + j * 4);
    float* p = agg + (size_t)d * N_FEATS + j * 4;
    atomicAdd(p + 0, v.x);
    atomicAdd(p + 1, v.y);
    atomicAdd(p + 2, v.z);
    atomicAdd(p + 3, v.w);
}

// ---------------------------------------------------------------------------
// fp32 VALU GEMM (fallback tiers), in place on d_out.
// ---------------------------------------------------------------------------
__launch_bounds__(256)
__global__ void gcn_gemm_inplace(float* __restrict__ out,
                                 const float* __restrict__ Wt,
                                 const float* __restrict__ b,
                                 int n_nodes) {
    __shared__ float a_lds[32 * N_FEATS];   // 16 KB

    const int t = threadIdx.x;
    const int node0 = blockIdx.x * 32;
    const int rows = min(32, n_nodes - node0);

    float4* a4 = reinterpret_cast<float4*>(a_lds);
    const float4* out4 = reinterpret_cast<const float4*>(out + (size_t)node0 * N_FEATS);
    const int nflt4 = rows * (N_FEATS / 4);
    for (int idx = t; idx < nflt4; idx += 256) a4[idx] = out4[idx];
    __syncthreads();

    const int oq = t & 31;
    const int ng = t >> 5;

    const float4 bb = reinterpret_cast<const float4*>(b)[oq];
    float4 acc[4];
#pragma unroll
    for (int k = 0; k < 4; ++k) acc[k] = bb;

    const float4* Wt4 = reinterpret_cast<const float4*>(Wt);
#pragma unroll 4
    for (int i = 0; i < N_FEATS; ++i) {
        const float4 w = Wt4[i * 32 + oq];
#pragma unroll
        for (int k = 0; k < 4; ++k) {
            const float a = a_lds[(ng * 4 + k) * N_FEATS + i];
            acc[k].x += a * w.x;
            acc[k].y += a * w.y;
            acc[k].z += a * w.z;
            acc[k].w += a * w.w;
        }
    }

    __syncthreads();

#pragma unroll
    for (int k = 0; k < 4; ++k) {
        const int r = ng * 4 + k;
        if (r < rows) {
            reinterpret_cast<float4*>(out + (size_t)(node0 + r) * N_FEATS)[oq] = acc[k];
        }
    }
}

extern "C" void kernel_launch(void* const* d_in, const int* in_sizes, int n_in,
                              void* d_out, int out_size, void* d_ws, size_t ws_size,
                              hipStream_t stream) {
    const float* feature = (const float*)d_in[0];
    const int*   src     = (const int*)d_in[1];
    const int*   dst     = (const int*)d_in[2];
    const float* W       = (const float*)d_in[3];
    const float* b       = (const float*)d_in[4];
    float* out = (float*)d_out;

    const int n_nodes = in_sizes[0] / N_FEATS;
    const int n_edges = in_sizes[1];
    const int nchunks = (n_nodes + SCAN_CHUNK - 1) / SCAN_CHUNK;

    // ---- workspace layout (256 B aligned) ----
    char* ws = (char*)d_ws;
    size_t off = 0;
    auto take = [&](size_t bytes) -> char* {
        char* p = ws + off;
        off = (off + bytes + 255) & ~(size_t)255;
        return p;
    };
    // common
    float* Wt        = (float*)take((size_t)N_FEATS * N_FEATS * sizeof(float));
    int*   deg       = (int*)  take((size_t)n_nodes * sizeof(int));
    int*   row_start = (int*)  take(((size_t)n_nodes + 1) * sizeof(int));
    int*   chunk_sum = (int*)  take((size_t)nchunks * sizeof(int));
    int*   csr_src   = (int*)  take((size_t)n_edges * sizeof(int));
    const size_t off_common = off;

    // tier A2: bf16 Y (transformed features) + bf16 W + pos
    unsigned short* Yb = (unsigned short*)take((size_t)n_nodes * N_FEATS * sizeof(unsigned short));
    unsigned short* Wb = (unsigned short*)take((size_t)N_FEATS * N_FEATS * sizeof(unsigned short));
    int* posA2 = (int*)take((size_t)n_edges * sizeof(int));
    const bool tierA2 = (off <= ws_size);
    // tier A: pos only (fp32 aggregate + fp32 GEMM)
    off = off_common;
    int* posA = (int*)take((size_t)n_edges * sizeof(int));
    const bool tierA = !tierA2 && (off <= ws_size);

    const int init_elems = N_FEATS * N_FEATS / 8 + N_FEATS * N_FEATS + n_nodes;

    if (tierA2 || tierA) {
        gcn_init<<<(init_elems + 255) / 256, 256, 0, stream>>>(
            W, tierA2 ? (float*)nullptr : Wt,
            tierA2 ? Wb : (unsigned short*)nullptr, deg, n_nodes);

        if (tierA2) {
            const long long nthr = (long long)((n_nodes + 15) / 16) * 64;
            gcn_transform_mfma<<<(int)((nthr + 255) / 256), 256, 0, stream>>>(
                feature, Wb, Yb, n_nodes);
        }

        const int eblocks = (n_edges + 255) / 256;
        int* pos = tierA2 ? posA2 : posA;
        gcn_hist_pos<<<eblocks, 256, 0, stream>>>(src, dst, deg, pos, n_edges, n_nodes);
        gcn_scan_part<<<nchunks, 256, 0, stream>>>(deg, chunk_sum, n_nodes);
        gcn_scan_final<<<nchunks, 256, 0, stream>>>(deg, chunk_sum, row_start,
                                                    n_nodes, nchunks);
        gcn_build_csr_pos<<<eblocks, 256, 0, stream>>>(
            src, dst, row_start, pos, csr_src, n_edges, n_nodes);
        if (tierA2) {
            gcn_aggregate_bf16<<<(n_nodes + 3) / 4, 256, 0, stream>>>(
                reinterpret_cast<const uint4*>(Yb), row_start, csr_src, b, out, n_nodes);
        } else {
            gcn_aggregate<<<(n_nodes + 3) / 4, 256, 0, stream>>>(
                feature, row_start, csr_src, out, n_nodes);
            gcn_gemm_inplace<<<(n_nodes + 31) / 32, 256, 0, stream>>>(out, Wt, b, n_nodes);
        }
    } else {
        // tier C: transpose init + atomic scatter + fp32 GEMM
        float* WtC = (float*)d_ws;   // 64 KB
        gcn_init<<<(init_elems + 255) / 256, 256, 0, stream>>>(
            W, WtC, (unsigned short*)nullptr, deg, 0);
        hipMemsetAsync(d_out, 0, (size_t)n_nodes * N_FEATS * sizeof(float), stream);
        long long total = (long long)n_edges * 32;
        gcn_scatter_add<<<(int)((total + 255) / 256), 256, 0, stream>>>(
            feature, src, dst, out, n_edges, n_nodes);
        gcn_gemm_inplace<<<(n_nodes + 31) / 32, 256, 0, stream>>>(out, WtC, b, n_nodes);
    }
}